// Round 3
// baseline (100.665 us; speedup 1.0000x reference)
//
#include <hip/hip_runtime.h>
#include <math.h>

#define S_LEN  4096
#define B_COLS 64
#define HDIM   512

typedef float v4f __attribute__((ext_vector_type(4)));

__device__ __forceinline__ float dot4(v4f a, v4f b) {
  return a.x * b.x + a.y * b.y + a.z * b.z + a.w * b.w;
}

// Kernel 1: s[t,b] = dot(hidden_states[t,b,:], W[:,0]) + b[0]
// One 64-lane wave per 8 rows per iteration; 16 independent 16B nontemporal
// loads in flight. Folded multi-value butterfly reduce: 10 shuffles / 8 rows.
// Scores written TRANSPOSED to ws[b*S + t] for kernel 2.
__global__ __launch_bounds__(256) void fc_scores_kernel(
    const float* __restrict__ hs,
    const float* __restrict__ W,
    const float* __restrict__ bias,
    float* __restrict__ ws) {
  const int lane = threadIdx.x & 63;
  const int wid  = (blockIdx.x * blockDim.x + threadIdx.x) >> 6;  // 0..8191
  constexpr int NW   = 2048 * 4;       // total waves
  constexpr int ROWS = S_LEN * B_COLS; // 262144

  const v4f* W4 = reinterpret_cast<const v4f*>(W);
  const v4f wv0 = W4[lane];
  const v4f wv1 = W4[64 + lane];
  const float bb = bias[0];

  for (int r0 = wid * 8; r0 < ROWS; r0 += NW * 8) {
    float p[8];
    #pragma unroll
    for (int u = 0; u < 8; ++u) {
      const v4f* H4 = reinterpret_cast<const v4f*>(hs + (size_t)(r0 + u) * HDIM);
      v4f a = __builtin_nontemporal_load(&H4[lane]);
      v4f c = __builtin_nontemporal_load(&H4[64 + lane]);
      p[u] = dot4(a, wv0) + dot4(c, wv1);
    }

    // Fold stage off=1: merge row pairs (0,1),(2,3),(4,5),(6,7).
    // Even lanes keep even row, odd lanes keep odd row. row bit0 = lane&1.
    float q[4];
    #pragma unroll
    for (int i = 0; i < 4; ++i) {
      float sendv = (lane & 1) ? p[2 * i] : p[2 * i + 1];
      float recv  = __shfl_xor(sendv, 1, 64);
      float keep  = (lane & 1) ? p[2 * i + 1] : p[2 * i];
      q[i] = keep + recv;
    }
    // Fold stage off=2: row bit1 = (lane&2)>>1.
    float r[2];
    #pragma unroll
    for (int i = 0; i < 2; ++i) {
      float sendv = (lane & 2) ? q[2 * i] : q[2 * i + 1];
      float recv  = __shfl_xor(sendv, 2, 64);
      float keep  = (lane & 2) ? q[2 * i + 1] : q[2 * i];
      r[i] = keep + recv;
    }
    // Fold stage off=4: row bit2 = (lane&4)>>2.
    {
      float sendv = (lane & 4) ? r[0] : r[1];
      float recv  = __shfl_xor(sendv, 4, 64);
      float keep  = (lane & 4) ? r[1] : r[0];
      r[0] = keep + recv;
    }
    // Plain butterflies across the eight 8-lane groups.
    float f = r[0];
    f += __shfl_xor(f, 8, 64);
    f += __shfl_xor(f, 16, 64);
    f += __shfl_xor(f, 32, 64);
    // Lane l (l<8) holds the full dot for row r0 + l.

    if (lane < 8) {
      int row = r0 + lane;
      int t = row >> 6, b = row & 63;
      ws[(size_t)b * S_LEN + t] = f + bb;
    }
  }
}

// Kernel 2: per-column reverse cumulative logsumexp + exp(s - lse).
// One block per column b; 1024 threads; thread owns 4 consecutive t loaded as
// one coalesced float4 from the transposed score buffer. 3-stage suffix scan:
// wave shuffle scan (no barriers) -> 16 wave aggregates in LDS (2 barriers).
__global__ __launch_bounds__(1024) void suffix_softmax_kernel(
    const float* __restrict__ ws, float* __restrict__ out) {
  const int b    = blockIdx.x;
  const int tid  = threadIdx.x;      // 0..1023
  const int lane = tid & 63;
  const int wv   = tid >> 6;         // 0..15
  constexpr int PER = 4;

  v4f v = *reinterpret_cast<const v4f*>(ws + (size_t)b * S_LEN + tid * PER);

  // Local aggregate over the thread's 4 elements.
  float m = fmaxf(fmaxf(v.x, v.y), fmaxf(v.z, v.w));
  float z = expf(v.x - m) + expf(v.y - m) + expf(v.z - m) + expf(v.w - m);

  // Wave reverse inclusive scan: (m,z)[lane] = aggregate of lanes [lane..63].
  #pragma unroll
  for (int off = 1; off < 64; off <<= 1) {
    float om = __shfl_down(m, off, 64);
    float oz = __shfl_down(z, off, 64);
    bool valid = (lane + off) < 64;
    om = valid ? om : -INFINITY;
    oz = valid ? oz : 0.f;
    float nm = fmaxf(m, om);
    z = z * expf(m - nm) + oz * expf(om - nm);  // om=-inf -> second term 0
    m = nm;
  }

  __shared__ float wm[16], wz[16];
  if (lane == 0) { wm[wv] = m; wz[wv] = z; }

  // Thread-exclusive suffix within the wave = inclusive value of lane+1.
  float em = __shfl_down(m, 1, 64);
  float ez = __shfl_down(z, 1, 64);
  if (lane == 63) { em = -INFINITY; ez = 0.f; }

  __syncthreads();

  // Wave-exclusive aggregate: combine waves wv+1..15 (broadcast LDS reads).
  float gm = -INFINITY, gz = 0.f;
  for (int w = wv + 1; w < 16; ++w) {
    float nm = fmaxf(gm, wm[w]);
    gz = gz * expf(gm - nm) + wz[w] * expf(wm[w] - nm);
    gm = nm;
  }

  // Total exclusive suffix for this thread (guard -inf - -inf = NaN).
  float tm = fmaxf(em, gm);
  float tz = (em > -INFINITY ? ez * expf(em - tm) : 0.f)
           + (gm > -INFINITY ? gz * expf(gm - tm) : 0.f);

  // Serial reverse pass over the 4 elements; emit selected = exp(s-M)/Z.
  float vals[4] = {v.x, v.y, v.z, v.w};
  float r[4];
  #pragma unroll
  for (int j = 3; j >= 0; --j) {
    float val = vals[j];
    float nm  = fmaxf(tm, val);
    float e   = expf(val - nm);
    tz = tz * expf(tm - nm) + e;   // tm=-inf -> first term 0 (nm finite)
    tm = nm;
    r[j] = e / tz;
  }
  #pragma unroll
  for (int j = 0; j < 4; ++j)
    out[(size_t)(tid * PER + j) * B_COLS + b] = r[j];
}

extern "C" void kernel_launch(void* const* d_in, const int* in_sizes, int n_in,
                              void* d_out, int out_size, void* d_ws, size_t ws_size,
                              hipStream_t stream) {
  const float* hs   = (const float*)d_in[0];
  const float* W    = (const float*)d_in[1];
  const float* bias = (const float*)d_in[2];
  float* out = (float*)d_out;       // [S, B, 1] == S*B floats
  float* ws  = (float*)d_ws;        // transposed scores [B][S], 1 MiB

  fc_scores_kernel<<<2048, 256, 0, stream>>>(hs, W, bias, ws);
  suffix_softmax_kernel<<<B_COLS, 1024, 0, stream>>>(ws, out);
}

// Round 4
// 92.050 us; speedup vs baseline: 1.0936x; 1.0936x over previous
//
#include <hip/hip_runtime.h>
#include <math.h>

#define S_LEN  4096
#define B_COLS 64
#define HDIM   512

typedef float v4f __attribute__((ext_vector_type(4)));

__device__ __forceinline__ float dot4(v4f a, v4f b) {
  return a.x * b.x + a.y * b.y + a.z * b.z + a.w * b.w;
}

// Kernel 1: s[t,b] = dot(hidden_states[t,b,:], W[:,0]) + b[0]
// One 64-lane wave per 4 rows per iteration; 8 independent 16B nontemporal
// loads in flight (round-2 structure). Folded butterfly reduce: 7 shuffles
// per 4 rows. Scores written TRANSPOSED to ws[b*S + t] for kernel 2.
__global__ __launch_bounds__(256) void fc_scores_kernel(
    const float* __restrict__ hs,
    const float* __restrict__ W,
    const float* __restrict__ bias,
    float* __restrict__ ws) {
  const int lane = threadIdx.x & 63;
  const int wid  = (blockIdx.x * blockDim.x + threadIdx.x) >> 6;  // 0..8191
  constexpr int NW   = 2048 * 4;       // total waves
  constexpr int ROWS = S_LEN * B_COLS; // 262144

  const v4f* W4 = reinterpret_cast<const v4f*>(W);
  const v4f wv0 = W4[lane];
  const v4f wv1 = W4[64 + lane];
  const float bb = bias[0];

  for (int r0 = wid * 4; r0 < ROWS; r0 += NW * 4) {
    float p[4];
    #pragma unroll
    for (int u = 0; u < 4; ++u) {
      const v4f* H4 = reinterpret_cast<const v4f*>(hs + (size_t)(r0 + u) * HDIM);
      v4f a = __builtin_nontemporal_load(&H4[lane]);
      v4f c = __builtin_nontemporal_load(&H4[64 + lane]);
      p[u] = dot4(a, wv0) + dot4(c, wv1);
    }

    // Fold stage off=1: merge row pairs (0,1),(2,3). Lane bit0 selects row bit0.
    float q[2];
    #pragma unroll
    for (int i = 0; i < 2; ++i) {
      float sendv = (lane & 1) ? p[2 * i] : p[2 * i + 1];
      float recv  = __shfl_xor(sendv, 1, 64);
      float keep  = (lane & 1) ? p[2 * i + 1] : p[2 * i];
      q[i] = keep + recv;
    }
    // Fold stage off=2: lane bit1 selects row bit1.
    float f;
    {
      float sendv = (lane & 2) ? q[0] : q[1];
      float recv  = __shfl_xor(sendv, 2, 64);
      float keep  = (lane & 2) ? q[1] : q[0];
      f = keep + recv;
    }
    // Plain butterflies: all 16 lanes with equal (lane&3) hold partials of
    // row r0 + (lane&3); sum them.
    f += __shfl_xor(f, 4, 64);
    f += __shfl_xor(f, 8, 64);
    f += __shfl_xor(f, 16, 64);
    f += __shfl_xor(f, 32, 64);

    if (lane < 4) {
      int row = r0 + lane;
      int t = row >> 6, b = row & 63;
      ws[(size_t)b * S_LEN + t] = f + bb;
    }
  }
}

// Kernel 2: per-column reverse cumulative logsumexp + exp(s - lse).
// One block per column b; 1024 threads; thread owns 4 consecutive t loaded as
// one coalesced float4 from the transposed score buffer. 3-stage suffix scan:
// wave shuffle scan (no barriers) -> 16 wave aggregates in LDS (2 barriers).
__global__ __launch_bounds__(1024) void suffix_softmax_kernel(
    const float* __restrict__ ws, float* __restrict__ out) {
  const int b    = blockIdx.x;
  const int tid  = threadIdx.x;      // 0..1023
  const int lane = tid & 63;
  const int wv   = tid >> 6;         // 0..15
  constexpr int PER = 4;

  v4f v = *reinterpret_cast<const v4f*>(ws + (size_t)b * S_LEN + tid * PER);

  // Local aggregate over the thread's 4 elements.
  float m = fmaxf(fmaxf(v.x, v.y), fmaxf(v.z, v.w));
  float z = expf(v.x - m) + expf(v.y - m) + expf(v.z - m) + expf(v.w - m);

  // Wave reverse inclusive scan: (m,z)[lane] = aggregate of lanes [lane..63].
  #pragma unroll
  for (int off = 1; off < 64; off <<= 1) {
    float om = __shfl_down(m, off, 64);
    float oz = __shfl_down(z, off, 64);
    bool valid = (lane + off) < 64;
    om = valid ? om : -INFINITY;
    oz = valid ? oz : 0.f;
    float nm = fmaxf(m, om);
    z = z * expf(m - nm) + oz * expf(om - nm);  // om=-inf -> second term 0
    m = nm;
  }

  __shared__ float wm[16], wz[16];
  if (lane == 0) { wm[wv] = m; wz[wv] = z; }

  // Thread-exclusive suffix within the wave = inclusive value of lane+1.
  float em = __shfl_down(m, 1, 64);
  float ez = __shfl_down(z, 1, 64);
  if (lane == 63) { em = -INFINITY; ez = 0.f; }

  __syncthreads();

  // Wave-exclusive aggregate: combine waves wv+1..15 (broadcast LDS reads).
  float gm = -INFINITY, gz = 0.f;
  for (int w = wv + 1; w < 16; ++w) {
    float nm = fmaxf(gm, wm[w]);
    gz = gz * expf(gm - nm) + wz[w] * expf(wm[w] - nm);
    gm = nm;
  }

  // Total exclusive suffix for this thread (guard -inf - -inf = NaN).
  float tm = fmaxf(em, gm);
  float tz = (em > -INFINITY ? ez * expf(em - tm) : 0.f)
           + (gm > -INFINITY ? gz * expf(gm - tm) : 0.f);

  // Serial reverse pass over the 4 elements; emit selected = exp(s-M)/Z.
  float vals[4] = {v.x, v.y, v.z, v.w};
  float r[4];
  #pragma unroll
  for (int j = 3; j >= 0; --j) {
    float val = vals[j];
    float nm  = fmaxf(tm, val);
    float e   = expf(val - nm);
    tz = tz * expf(tm - nm) + e;   // tm=-inf -> first term 0 (nm finite)
    tm = nm;
    r[j] = e / tz;
  }
  #pragma unroll
  for (int j = 0; j < 4; ++j)
    out[(size_t)(tid * PER + j) * B_COLS + b] = r[j];
}

extern "C" void kernel_launch(void* const* d_in, const int* in_sizes, int n_in,
                              void* d_out, int out_size, void* d_ws, size_t ws_size,
                              hipStream_t stream) {
  const float* hs   = (const float*)d_in[0];
  const float* W    = (const float*)d_in[1];
  const float* bias = (const float*)d_in[2];
  float* out = (float*)d_out;       // [S, B, 1] == S*B floats
  float* ws  = (float*)d_ws;        // transposed scores [B][S], 1 MiB

  fc_scores_kernel<<<2048, 256, 0, stream>>>(hs, W, bias, ws);
  suffix_softmax_kernel<<<B_COLS, 1024, 0, stream>>>(ws, out);
}

// Round 5
// 91.930 us; speedup vs baseline: 1.0950x; 1.0013x over previous
//
#include <hip/hip_runtime.h>
#include <math.h>

#define S_LEN  4096
#define B_COLS 64
#define HDIM   512

typedef float v4f __attribute__((ext_vector_type(4)));

__device__ __forceinline__ float dot4(v4f a, v4f b) {
  return a.x * b.x + a.y * b.y + a.z * b.z + a.w * b.w;
}

// Kernel 1: s[t,b] = dot(hidden_states[t,b,:], W[:,0]) + b[0]
// One 64-lane wave per 4 rows per iteration; 8 independent 16B nontemporal
// loads in flight. Folded butterfly reduce: 7 shuffles per 4 rows.
// __launch_bounds__(256, 8): force <=64 VGPR so 8 waves/SIMD are resident —
// this kernel is pure streaming and lives on TLP.
// Scores written TRANSPOSED to ws[b*S + t] for kernel 2.
__global__ __launch_bounds__(256, 8) void fc_scores_kernel(
    const float* __restrict__ hs,
    const float* __restrict__ W,
    const float* __restrict__ bias,
    float* __restrict__ ws) {
  const int lane = threadIdx.x & 63;
  const int wid  = (blockIdx.x * blockDim.x + threadIdx.x) >> 6;  // 0..8191
  constexpr int NW   = 2048 * 4;       // total waves
  constexpr int ROWS = S_LEN * B_COLS; // 262144

  const v4f* W4 = reinterpret_cast<const v4f*>(W);
  const v4f wv0 = W4[lane];
  const v4f wv1 = W4[64 + lane];
  const float bb = bias[0];

  for (int r0 = wid * 4; r0 < ROWS; r0 += NW * 4) {
    float p[4];
    #pragma unroll
    for (int u = 0; u < 4; ++u) {
      const v4f* H4 = reinterpret_cast<const v4f*>(hs + (size_t)(r0 + u) * HDIM);
      v4f a = __builtin_nontemporal_load(&H4[lane]);
      v4f c = __builtin_nontemporal_load(&H4[64 + lane]);
      p[u] = dot4(a, wv0) + dot4(c, wv1);
    }

    // Fold stage off=1: merge row pairs (0,1),(2,3). Lane bit0 selects row bit0.
    float q[2];
    #pragma unroll
    for (int i = 0; i < 2; ++i) {
      float sendv = (lane & 1) ? p[2 * i] : p[2 * i + 1];
      float recv  = __shfl_xor(sendv, 1, 64);
      float keep  = (lane & 1) ? p[2 * i + 1] : p[2 * i];
      q[i] = keep + recv;
    }
    // Fold stage off=2: lane bit1 selects row bit1.
    float f;
    {
      float sendv = (lane & 2) ? q[0] : q[1];
      float recv  = __shfl_xor(sendv, 2, 64);
      float keep  = (lane & 2) ? q[1] : q[0];
      f = keep + recv;
    }
    // Plain butterflies: all 16 lanes with equal (lane&3) hold partials of
    // row r0 + (lane&3); sum them.
    f += __shfl_xor(f, 4, 64);
    f += __shfl_xor(f, 8, 64);
    f += __shfl_xor(f, 16, 64);
    f += __shfl_xor(f, 32, 64);

    if (lane < 4) {
      int row = r0 + lane;
      int t = row >> 6, b = row & 63;
      ws[(size_t)b * S_LEN + t] = f + bb;
    }
  }
}

// Kernel 2: per-column reverse cumulative logsumexp + exp(s - lse).
// One block per column b; 1024 threads; thread owns 4 consecutive t loaded as
// one coalesced float4 from the transposed score buffer. 3-stage suffix scan:
// wave shuffle scan (no barriers) -> 16 wave aggregates in LDS (2 barriers).
__global__ __launch_bounds__(1024) void suffix_softmax_kernel(
    const float* __restrict__ ws, float* __restrict__ out) {
  const int b    = blockIdx.x;
  const int tid  = threadIdx.x;      // 0..1023
  const int lane = tid & 63;
  const int wv   = tid >> 6;         // 0..15
  constexpr int PER = 4;

  v4f v = *reinterpret_cast<const v4f*>(ws + (size_t)b * S_LEN + tid * PER);

  // Local aggregate over the thread's 4 elements.
  float m = fmaxf(fmaxf(v.x, v.y), fmaxf(v.z, v.w));
  float z = expf(v.x - m) + expf(v.y - m) + expf(v.z - m) + expf(v.w - m);

  // Wave reverse inclusive scan: (m,z)[lane] = aggregate of lanes [lane..63].
  #pragma unroll
  for (int off = 1; off < 64; off <<= 1) {
    float om = __shfl_down(m, off, 64);
    float oz = __shfl_down(z, off, 64);
    bool valid = (lane + off) < 64;
    om = valid ? om : -INFINITY;
    oz = valid ? oz : 0.f;
    float nm = fmaxf(m, om);
    z = z * expf(m - nm) + oz * expf(om - nm);  // om=-inf -> second term 0
    m = nm;
  }

  __shared__ float wm[16], wz[16];
  if (lane == 0) { wm[wv] = m; wz[wv] = z; }

  // Thread-exclusive suffix within the wave = inclusive value of lane+1.
  float em = __shfl_down(m, 1, 64);
  float ez = __shfl_down(z, 1, 64);
  if (lane == 63) { em = -INFINITY; ez = 0.f; }

  __syncthreads();

  // Wave-exclusive aggregate: combine waves wv+1..15 (broadcast LDS reads).
  float gm = -INFINITY, gz = 0.f;
  for (int w = wv + 1; w < 16; ++w) {
    float nm = fmaxf(gm, wm[w]);
    gz = gz * expf(gm - nm) + wz[w] * expf(wm[w] - nm);
    gm = nm;
  }

  // Total exclusive suffix for this thread (guard -inf - -inf = NaN).
  float tm = fmaxf(em, gm);
  float tz = (em > -INFINITY ? ez * expf(em - tm) : 0.f)
           + (gm > -INFINITY ? gz * expf(gm - tm) : 0.f);

  // Serial reverse pass over the 4 elements; emit selected = exp(s-M)/Z.
  float vals[4] = {v.x, v.y, v.z, v.w};
  float r[4];
  #pragma unroll
  for (int j = 3; j >= 0; --j) {
    float val = vals[j];
    float nm  = fmaxf(tm, val);
    float e   = expf(val - nm);
    tz = tz * expf(tm - nm) + e;   // tm=-inf -> first term 0 (nm finite)
    tm = nm;
    r[j] = e / tz;
  }
  #pragma unroll
  for (int j = 0; j < 4; ++j)
    out[(size_t)(tid * PER + j) * B_COLS + b] = r[j];
}

extern "C" void kernel_launch(void* const* d_in, const int* in_sizes, int n_in,
                              void* d_out, int out_size, void* d_ws, size_t ws_size,
                              hipStream_t stream) {
  const float* hs   = (const float*)d_in[0];
  const float* W    = (const float*)d_in[1];
  const float* bias = (const float*)d_in[2];
  float* out = (float*)d_out;       // [S, B, 1] == S*B floats
  float* ws  = (float*)d_ws;        // transposed scores [B][S], 1 MiB

  fc_scores_kernel<<<2048, 256, 0, stream>>>(hs, W, bias, ws);
  suffix_softmax_kernel<<<B_COLS, 1024, 0, stream>>>(ws, out);
}